// Round 1
// baseline (3729.787 us; speedup 1.0000x reference)
//
#include <hip/hip_runtime.h>
#include <stdint.h>

// Problem dims
#define T_DIM 512
#define B_DIM 256
#define IN_DIM 256
#define H_DIM 256

typedef unsigned short ushortT;
typedef __attribute__((ext_vector_type(8))) short short8;     // 8 x bf16 (MFMA frag)
typedef __attribute__((ext_vector_type(4))) float float4v;    // MFMA acc
typedef __attribute__((ext_vector_type(4))) int int4v;
typedef __attribute__((ext_vector_type(4))) unsigned short ushort4v;

// ---- workspace layout (bytes) ----
#define OFF_HDR      0            // int[3]: K, maxlen, mask_mode
#define OFF_FLAGS    256          // 64 flags, 64B apart (4KB)
#define OFF_LEN      8192         // int[256]
#define OFF_CUMM     12288        // int[512]
#define OFF_CUMP     16384        // int[512]
#define OFF_MTI      32768        // int[131072]  maskTrueIdx
#define OFF_PARR     557056       // int[131072]  p_array (packed rank or -1)
#define OFF_HBUF     1081344      // float[2][256][256] ping-pong h
#define OFF_WIH      1605632      // bf16[768*256]
#define OFF_WHH      1998848      // bf16[768*256]
#define OFF_COMPACT  2392064      // bf16[131072*256] gathered x (packed order)
#define OFF_GI       69500928     // bf16[131072*768] input projections (packed order)

__device__ __forceinline__ ushortT f2bf(float f) {
  unsigned u = __float_as_uint(f);
  unsigned r = (u + 0x7fffu + ((u >> 16) & 1u)) >> 16;
  return (ushortT)r;
}
__device__ __forceinline__ float bf2f(ushortT h) {
  return __uint_as_float(((unsigned)h) << 16);
}
__device__ __forceinline__ float sigf(float x) { return 1.f / (1.f + __expf(-x)); }
__device__ __forceinline__ float tanhfast(float x) { return 1.f - 2.f / (1.f + __expf(2.f * x)); }

// ---------------- k_prep: lengths, row/col sums, scans, mask dtype detect ----------------
__global__ __launch_bounds__(512) void k_prep(const int* __restrict__ mask, int* __restrict__ wsi) {
  __shared__ int m_s[512], colp[512], len_s[256], sA[512], sB[512];
  __shared__ int sh_mode;
  const int tid = threadIdx.x;
  if (tid == 0) sh_mode = 0;
  __syncthreads();
  // detect: bool-byte mask (any 4B word > 1) vs int32 0/1 mask
  int bad = 0;
  for (int i = tid; i < 32768; i += 512) {
    unsigned v = ((const unsigned*)mask)[i];
    if (v > 1u) bad = 1;
  }
  if (bad) atomicOr(&sh_mode, 1);
  __syncthreads();
  const int mode = sh_mode;

  // row sums m_t (thread = row t)
  int s = 0;
  if (mode) {
    const unsigned char* mb = (const unsigned char*)mask;
    for (int c = 0; c < 256; c += 4) {
      unsigned v = *(const unsigned*)(mb + tid * 256 + c);
      s += (v & 0xff) + ((v >> 8) & 0xff) + ((v >> 16) & 0xff) + ((v >> 24) & 0xff);
    }
  } else {
    const int4v* mr = (const int4v*)(mask + tid * 256);
    for (int c = 0; c < 64; ++c) { int4v v = mr[c]; s += v[0] + v[1] + v[2] + v[3]; }
  }
  m_s[tid] = s;

  // col sums (two half-ranges per column)
  const int b = tid & 255, hh = tid >> 8;
  int cs = 0;
  if (mode) {
    const unsigned char* mb = (const unsigned char*)mask;
    for (int r = hh * 256; r < hh * 256 + 256; ++r) cs += mb[r * 256 + b];
  } else {
    for (int r = hh * 256; r < hh * 256 + 256; ++r) cs += mask[r * 256 + b];
  }
  colp[tid] = cs;
  __syncthreads();
  if (tid < 256) len_s[tid] = colp[tid] + colp[tid + 256];
  __syncthreads();

  // n_t = #{b : len_b > t}
  int nt = 0;
  for (int i = 0; i < 256; ++i) nt += (len_s[i] > tid) ? 1 : 0;

  // inclusive scans (Hillis-Steele) of m_t and n_t
  sA[tid] = m_s[tid]; sB[tid] = nt;
  for (int off = 1; off < 512; off <<= 1) {
    __syncthreads();
    int am = (tid >= off) ? sA[tid - off] : 0;
    int an = (tid >= off) ? sB[tid - off] : 0;
    __syncthreads();
    sA[tid] += am; sB[tid] += an;
  }
  __syncthreads();
  wsi[OFF_CUMM / 4 + tid] = sA[tid] - m_s[tid];  // exclusive
  wsi[OFF_CUMP / 4 + tid] = sB[tid] - nt;        // exclusive
  if (tid < 256) wsi[OFF_LEN / 4 + tid] = len_s[tid];

  // maxlen
  colp[tid] = (tid < 256) ? len_s[tid] : 0;
  for (int off = 256; off >= 1; off >>= 1) {
    __syncthreads();
    int o = (tid < off) ? colp[tid + off] : 0;
    __syncthreads();
    if (tid < off) colp[tid] = max(colp[tid], o);
  }
  __syncthreads();
  if (tid == 0) { wsi[0] = sA[511]; wsi[1] = colp[0]; wsi[2] = mode; }
}

// ---------------- k_build: per-row scans -> maskTrueIdx and p_array ----------------
__global__ __launch_bounds__(256) void k_build(const int* __restrict__ mask, int* __restrict__ wsi) {
  const int t = blockIdx.x, b = threadIdx.x;
  const int mode = wsi[2];
  const int lane = b & 63, wv = b >> 6;
  int mflag = mode ? (int)((const unsigned char*)mask)[t * 256 + b] : mask[t * 256 + b];
  mflag = mflag ? 1 : 0;
  const int len = wsi[OFF_LEN / 4 + b];
  const int pflag = (t < len) ? 1 : 0;
  unsigned long long bm = __ballot(mflag), bp = __ballot(pflag);
  __shared__ int wm[4], wp[4];
  if (lane == 0) { wm[wv] = __popcll(bm); wp[wv] = __popcll(bp); }
  __syncthreads();
  int baseM = 0, baseP = 0;
  for (int i = 0; i < wv; ++i) { baseM += wm[i]; baseP += wp[i]; }
  unsigned long long lt = (1ull << lane) - 1ull;
  const int moff = baseM + __popcll(bm & lt);
  const int poff = baseP + __popcll(bp & lt);
  const int j = t * 256 + b;
  if (mflag) wsi[OFF_MTI / 4 + wsi[OFF_CUMM / 4 + t] + moff] = j;
  wsi[OFF_PARR / 4 + j] = pflag ? (wsi[OFF_CUMP / 4 + t] + poff) : -1;
}

// ---------------- k_wcvt: W_ih, W_hh fp32 -> bf16 ----------------
__global__ __launch_bounds__(256) void k_wcvt(const float* __restrict__ Wih,
                                              const float* __restrict__ Whh,
                                              int* __restrict__ wsi) {
  const int idx = (blockIdx.x * 256 + threadIdx.x) * 4;
  const float* src;
  ushortT* dst;
  if (idx < 196608) { src = Wih + idx; dst = (ushortT*)((char*)wsi + OFF_WIH) + idx; }
  else { src = Whh + (idx - 196608); dst = (ushortT*)((char*)wsi + OFF_WHH) + (idx - 196608); }
  float4v v = *(const float4v*)src;
  ushort4v o;
  o[0] = f2bf(v[0]); o[1] = f2bf(v[1]); o[2] = f2bf(v[2]); o[3] = f2bf(v[3]);
  *(ushort4v*)dst = o;
}

// ---------------- k_gather: compact[p] = bf16(x[maskTrueIdx[p]]) ----------------
__global__ __launch_bounds__(256) void k_gather(const float* __restrict__ x, int* __restrict__ wsi) {
  const int K = wsi[0];
  const int p = blockIdx.x * 16 + (threadIdx.x >> 4);
  if (p >= K) return;
  const int lc = threadIdx.x & 15;
  const int src = wsi[OFF_MTI / 4 + p];
  const float4v* xr = (const float4v*)(x + (size_t)src * 256);
  ushortT* cp_ = (ushortT*)((char*)wsi + OFF_COMPACT) + (size_t)p * 256;
#pragma unroll
  for (int k = 0; k < 4; ++k) {
    float4v v = xr[k * 16 + lc];
    ushort4v o;
    o[0] = f2bf(v[0]); o[1] = f2bf(v[1]); o[2] = f2bf(v[2]); o[3] = f2bf(v[3]);
    *(ushort4v*)(cp_ + k * 64 + lc * 4) = o;
  }
}

// ---------------- k_gemm: gi[p][0..767] = compact[p] @ W_ih^T (bf16 MFMA) ----------------
__global__ __launch_bounds__(256, 2) void k_gemm(int* __restrict__ wsi) {
  const int K = wsi[0];
  const int m0 = blockIdx.x * 128;
  if (m0 >= K) return;
  const int n0 = blockIdx.y * 128;
  char* wsc = (char*)wsi;
  const ushortT* A = (const ushortT*)(wsc + OFF_COMPACT);
  const ushortT* B = (const ushortT*)(wsc + OFF_WIH);
  ushortT* C = (ushortT*)(wsc + OFF_GI);
  __shared__ ushortT As[128 * 72], Bs[128 * 72];  // +8 pad per 64-col row: conflict-free
  const int tid = threadIdx.x, w = tid >> 6, lane = tid & 63;
  const int l15 = lane & 15, quad = lane >> 4;
  float4v acc[4][4];
#pragma unroll
  for (int i = 0; i < 4; ++i)
#pragma unroll
    for (int j = 0; j < 4; ++j) acc[i][j] = (float4v){0.f, 0.f, 0.f, 0.f};

  for (int k0 = 0; k0 < 256; k0 += 64) {
    __syncthreads();
#pragma unroll
    for (int i = 0; i < 4; ++i) {
      int cid = i * 256 + tid;
      int row = cid >> 3, c8 = cid & 7;
      int4v va = *(const int4v*)(A + (size_t)(m0 + row) * 256 + k0 + c8 * 8);
      *(int4v*)(As + row * 72 + c8 * 8) = va;
      int4v vb = *(const int4v*)(B + (size_t)(n0 + row) * 256 + k0 + c8 * 8);
      *(int4v*)(Bs + row * 72 + c8 * 8) = vb;
    }
    __syncthreads();
#pragma unroll
    for (int kk = 0; kk < 2; ++kk) {
      short8 af[4], bfr[4];
#pragma unroll
      for (int i = 0; i < 4; ++i)
        af[i] = *(const short8*)(As + ((w >> 1) * 64 + i * 16 + l15) * 72 + kk * 32 + quad * 8);
#pragma unroll
      for (int j = 0; j < 4; ++j)
        bfr[j] = *(const short8*)(Bs + ((w & 1) * 64 + j * 16 + l15) * 72 + kk * 32 + quad * 8);
#pragma unroll
      for (int i = 0; i < 4; ++i)
#pragma unroll
        for (int j = 0; j < 4; ++j)
          acc[i][j] = __builtin_amdgcn_mfma_f32_16x16x32_bf16(af[i], bfr[j], acc[i][j], 0, 0, 0);
    }
  }
#pragma unroll
  for (int i = 0; i < 4; ++i) {
    int m = m0 + (w >> 1) * 64 + i * 16 + quad * 4;
#pragma unroll
    for (int j = 0; j < 4; ++j) {
      int n = n0 + (w & 1) * 64 + j * 16 + l15;
#pragma unroll
      for (int r = 0; r < 4; ++r)
        C[(size_t)(m + r) * 768 + n] = f2bf(acc[i][j][r]);
    }
  }
}

// ---------------- k_rec: persistent GRU recurrence ----------------
// grid 64: blockIdx -> batch-group gid (&15), col-group jj (>>4) so the 4 group
// members share blockIdx%8 (same-XCD heuristic). W_hh slice lives in VGPRs.
__global__ __launch_bounds__(256, 1) void k_rec(const float* __restrict__ bih,
                                                const float* __restrict__ bhh,
                                                const float* __restrict__ h0,
                                                int* __restrict__ wsi,
                                                float* __restrict__ out) {
  const int gid = blockIdx.x & 15;
  const int jj = blockIdx.x >> 4;
  const int b0 = gid * 16, c0 = jj * 64;
  const int tid = threadIdx.x, w = tid >> 6, lane = tid & 63;
  const int l15 = lane & 15, quad = lane >> 4;
  char* wsc = (char*)wsi;
  const ushortT* Whh = (const ushortT*)(wsc + OFF_WHH);
  const ushortT* gib = (const ushortT*)(wsc + OFF_GI);
  const int* parr = wsi + OFF_PARR / 4;
  const int* mti = wsi + OFF_MTI / 4;
  int* flags = wsi + OFF_FLAGS / 4;
  float* hb = (float*)(wsc + OFF_HBUF);
  const int K = wsi[0], maxlen = wsi[1];

  __shared__ ushortT h_s[16 * 264];  // 16 batches x (256 + 8 pad) bf16
  __shared__ float bih_s[192], bhh_s[192];
  __shared__ int len_s[16];
  if (tid < 192) { int g = tid >> 6, c = tid & 63; bih_s[tid] = bih[g * 256 + c0 + c]; bhh_s[tid] = bhh[g * 256 + c0 + c]; }
  if (tid < 16) len_s[tid] = wsi[OFF_LEN / 4 + b0 + tid];

  // W_hh fragments resident in registers: wf[gate][kk]
  short8 wf[3][8];
#pragma unroll
  for (int g = 0; g < 3; ++g)
#pragma unroll
    for (int kk = 0; kk < 8; ++kk) {
      int row = g * 256 + c0 + w * 16 + l15;
      wf[g][kk] = *(const short8*)(Whh + row * 256 + kk * 32 + quad * 8);
    }

  const int cl = w * 16 + l15, cg = c0 + cl;
  float hreg[4];  // fp32 h carried in registers for (batch = quad*4+r, col = cg)
#pragma unroll
  for (int r = 0; r < 4; ++r) hreg[r] = h0[(b0 + quad * 4 + r) * 256 + cg];
  __syncthreads();

  for (int t = 0; t < maxlen; ++t) {
    // stage h (fp32 global, agent-coherent) -> bf16 LDS
    {
      const unsigned long long* hs = (const unsigned long long*)(hb + (t & 1) * 65536 + b0 * 256);
#pragma unroll
      for (int q = 0; q < 8; ++q) {
        int idx = q * 256 + tid;
        int row = idx >> 7, cp = idx & 127;
        unsigned long long v = __hip_atomic_load(hs + row * 128 + cp, __ATOMIC_RELAXED, __HIP_MEMORY_SCOPE_AGENT);
        float f0 = __uint_as_float((unsigned)v);
        float f1 = __uint_as_float((unsigned)(v >> 32));
        unsigned pk = (unsigned)f2bf(f0) | ((unsigned)f2bf(f1) << 16);
        *(unsigned*)((char*)h_s + row * 528 + cp * 4) = pk;
      }
    }
    __syncthreads();

    float4v acc0 = {0.f, 0.f, 0.f, 0.f}, acc1 = {0.f, 0.f, 0.f, 0.f}, acc2 = {0.f, 0.f, 0.f, 0.f};
#pragma unroll
    for (int kk = 0; kk < 8; ++kk) {
      short8 a = *(const short8*)((const char*)h_s + l15 * 528 + kk * 64 + quad * 16);
      acc0 = __builtin_amdgcn_mfma_f32_16x16x32_bf16(a, wf[0][kk], acc0, 0, 0, 0);
      acc1 = __builtin_amdgcn_mfma_f32_16x16x32_bf16(a, wf[1][kk], acc1, 0, 0, 0);
      acc2 = __builtin_amdgcn_mfma_f32_16x16x32_bf16(a, wf[2][kk], acc2, 0, 0, 0);
    }

    float* hdst = hb + ((t + 1) & 1) * 65536;
    const int nfb = t * 256 + b0;
#pragma unroll
    for (int r = 0; r < 4; ++r) {
      int batch = quad * 4 + r, bg = b0 + batch;
      float hnew;
      if (t < len_s[batch]) {
        int p = parr[nfb + batch];
        const ushortT* grow = gib + (size_t)p * 768;
        float girv = bf2f(grow[cg]);
        float gizv = bf2f(grow[256 + cg]);
        float ginv = bf2f(grow[512 + cg]);
        float rr = sigf(girv + bih_s[cl] + acc0[r] + bhh_s[cl]);
        float zz = sigf(gizv + bih_s[64 + cl] + acc1[r] + bhh_s[64 + cl]);
        float nn = tanhfast(ginv + bih_s[128 + cl] + rr * (acc2[r] + bhh_s[128 + cl]));
        hnew = (1.f - zz) * nn + zz * hreg[r];
        int nflat = nfb + batch;
        if (nflat < K) out[(size_t)mti[nflat] * 256 + cg] = hnew;  // scatter
      } else {
        hnew = hreg[r];
      }
      hreg[r] = hnew;
      __hip_atomic_store(hdst + bg * 256 + cg, hnew, __ATOMIC_RELAXED, __HIP_MEMORY_SCOPE_AGENT);
    }
    __threadfence();
    __syncthreads();
    if (tid == 0)
      __hip_atomic_store(&flags[(gid * 4 + jj) * 16], t + 1, __ATOMIC_RELEASE, __HIP_MEMORY_SCOPE_AGENT);
    if (tid < 4) {
      while (__hip_atomic_load(&flags[(gid * 4 + tid) * 16], __ATOMIC_ACQUIRE, __HIP_MEMORY_SCOPE_AGENT) < t + 1)
        __builtin_amdgcn_s_sleep(1);
      __threadfence();
    }
    __syncthreads();
  }

  // h_last (fp32) from carried registers
#pragma unroll
  for (int r = 0; r < 4; ++r)
    out[33554432 + (size_t)(b0 + quad * 4 + r) * 256 + cg] = hreg[r];
}

extern "C" void kernel_launch(void* const* d_in, const int* in_sizes, int n_in,
                              void* d_out, int out_size, void* d_ws, size_t ws_size,
                              hipStream_t stream) {
  const float* x = (const float*)d_in[0];
  const float* h0 = (const float*)d_in[1];
  const int* mask = (const int*)d_in[2];
  const float* Wih = (const float*)d_in[3];
  const float* Whh = (const float*)d_in[4];
  const float* bih = (const float*)d_in[5];
  const float* bhh = (const float*)d_in[6];
  float* out = (float*)d_out;
  char* ws = (char*)d_ws;
  int* wsi = (int*)d_ws;

  hipMemsetAsync(d_out, 0, (size_t)out_size * 4, stream);      // scores default 0
  hipMemsetAsync(d_ws, 0, 8192, stream);                       // header + flags
  hipMemcpyAsync(ws + OFF_HBUF, d_in[1], 65536 * 4, hipMemcpyDeviceToDevice, stream);  // h ping-pong init

  k_prep<<<1, 512, 0, stream>>>(mask, wsi);
  k_build<<<512, 256, 0, stream>>>(mask, wsi);
  k_wcvt<<<384, 256, 0, stream>>>(Wih, Whh, wsi);
  k_gather<<<8192, 256, 0, stream>>>(x, wsi);
  k_gemm<<<dim3(1024, 6), 256, 0, stream>>>(wsi);
  k_rec<<<64, 256, 0, stream>>>(bih, bhh, h0, wsi, out);
}

// Round 2
// 1580.502 us; speedup vs baseline: 2.3599x; 2.3599x over previous
//
#include <hip/hip_runtime.h>
#include <stdint.h>

typedef unsigned short ushortT;
typedef __attribute__((ext_vector_type(8))) short short8;     // 8 x bf16 (MFMA frag)
typedef __attribute__((ext_vector_type(4))) float float4v;
typedef __attribute__((ext_vector_type(4))) int int4v;
typedef __attribute__((ext_vector_type(4))) unsigned short ushort4v;

// ---- workspace layout (bytes) ----
#define OFF_HDR      0            // int[3]: K, maxlen, mask_mode
#define OFF_LEN      8192         // int[256]
#define OFF_CUMM     12288        // int[512]
#define OFF_CUMP     16384        // int[512]
#define OFF_MTI      32768        // int[131072]  maskTrueIdx
#define OFF_PARR     557056       // int[131072]  p_array (packed rank or -1)
#define OFF_WIH      1605632      // bf16[768*256]
#define OFF_WHH      1998848      // bf16[768*256]
#define OFF_GI       2392064      // bf16[131072*768] input projections (packed order)

#define HLAST_OFF    33554432     // floats: T*B*H

__device__ __forceinline__ ushortT f2bf(float f) {
  unsigned u = __float_as_uint(f);
  unsigned r = (u + 0x7fffu + ((u >> 16) & 1u)) >> 16;
  return (ushortT)r;
}
__device__ __forceinline__ float bf2f(ushortT h) {
  return __uint_as_float(((unsigned)h) << 16);
}
__device__ __forceinline__ float sigf(float x) { return 1.f / (1.f + __expf(-x)); }
__device__ __forceinline__ float tanhfast(float x) { return 1.f - 2.f / (1.f + __expf(2.f * x)); }

// ---------------- k_prep: lengths, row/col sums, scans, mask dtype detect ----------------
__global__ __launch_bounds__(512) void k_prep(const int* __restrict__ mask, int* __restrict__ wsi) {
  __shared__ int m_s[512], colp[512], len_s[256], sA[512], sB[512];
  __shared__ int sh_mode;
  const int tid = threadIdx.x;
  if (tid == 0) sh_mode = 0;
  __syncthreads();
  int bad = 0;
  for (int i = tid; i < 32768; i += 512) {
    unsigned v = ((const unsigned*)mask)[i];
    if (v > 1u) bad = 1;
  }
  if (bad) atomicOr(&sh_mode, 1);
  __syncthreads();
  const int mode = sh_mode;

  int s = 0;
  if (mode) {
    const unsigned char* mb = (const unsigned char*)mask;
    for (int c = 0; c < 256; c += 4) {
      unsigned v = *(const unsigned*)(mb + tid * 256 + c);
      s += (v & 0xff) + ((v >> 8) & 0xff) + ((v >> 16) & 0xff) + ((v >> 24) & 0xff);
    }
  } else {
    const int4v* mr = (const int4v*)(mask + tid * 256);
    for (int c = 0; c < 64; ++c) { int4v v = mr[c]; s += v[0] + v[1] + v[2] + v[3]; }
  }
  m_s[tid] = s;

  const int b = tid & 255, hh = tid >> 8;
  int cs = 0;
  if (mode) {
    const unsigned char* mb = (const unsigned char*)mask;
    for (int r = hh * 256; r < hh * 256 + 256; ++r) cs += mb[r * 256 + b];
  } else {
    for (int r = hh * 256; r < hh * 256 + 256; ++r) cs += mask[r * 256 + b];
  }
  colp[tid] = cs;
  __syncthreads();
  if (tid < 256) len_s[tid] = colp[tid] + colp[tid + 256];
  __syncthreads();

  int nt = 0;
  for (int i = 0; i < 256; ++i) nt += (len_s[i] > tid) ? 1 : 0;

  sA[tid] = m_s[tid]; sB[tid] = nt;
  for (int off = 1; off < 512; off <<= 1) {
    __syncthreads();
    int am = (tid >= off) ? sA[tid - off] : 0;
    int an = (tid >= off) ? sB[tid - off] : 0;
    __syncthreads();
    sA[tid] += am; sB[tid] += an;
  }
  __syncthreads();
  wsi[OFF_CUMM / 4 + tid] = sA[tid] - m_s[tid];
  wsi[OFF_CUMP / 4 + tid] = sB[tid] - nt;
  if (tid < 256) wsi[OFF_LEN / 4 + tid] = len_s[tid];

  colp[tid] = (tid < 256) ? len_s[tid] : 0;
  for (int off = 256; off >= 1; off >>= 1) {
    __syncthreads();
    int o = (tid < off) ? colp[tid + off] : 0;
    __syncthreads();
    if (tid < off) colp[tid] = max(colp[tid], o);
  }
  __syncthreads();
  if (tid == 0) { wsi[0] = sA[511]; wsi[1] = colp[0]; wsi[2] = mode; }
}

// ---------------- k_build: per-row scans -> maskTrueIdx and p_array ----------------
__global__ __launch_bounds__(256) void k_build(const int* __restrict__ mask, int* __restrict__ wsi) {
  const int t = blockIdx.x, b = threadIdx.x;
  const int mode = wsi[2];
  const int lane = b & 63, wv = b >> 6;
  int mflag = mode ? (int)((const unsigned char*)mask)[t * 256 + b] : mask[t * 256 + b];
  mflag = mflag ? 1 : 0;
  const int len = wsi[OFF_LEN / 4 + b];
  const int pflag = (t < len) ? 1 : 0;
  unsigned long long bm = __ballot(mflag), bp = __ballot(pflag);
  __shared__ int wm[4], wp[4];
  if (lane == 0) { wm[wv] = __popcll(bm); wp[wv] = __popcll(bp); }
  __syncthreads();
  int baseM = 0, baseP = 0;
  for (int i = 0; i < wv; ++i) { baseM += wm[i]; baseP += wp[i]; }
  unsigned long long lt = (1ull << lane) - 1ull;
  const int moff = baseM + __popcll(bm & lt);
  const int poff = baseP + __popcll(bp & lt);
  const int j = t * 256 + b;
  if (mflag) wsi[OFF_MTI / 4 + wsi[OFF_CUMM / 4 + t] + moff] = j;
  wsi[OFF_PARR / 4 + j] = pflag ? (wsi[OFF_CUMP / 4 + t] + poff) : -1;
}

// ---------------- k_wcvt: W_ih, W_hh fp32 -> bf16 ----------------
__global__ __launch_bounds__(256) void k_wcvt(const float* __restrict__ Wih,
                                              const float* __restrict__ Whh,
                                              int* __restrict__ wsi) {
  const int idx = (blockIdx.x * 256 + threadIdx.x) * 4;
  const float* src;
  ushortT* dst;
  if (idx < 196608) { src = Wih + idx; dst = (ushortT*)((char*)wsi + OFF_WIH) + idx; }
  else { src = Whh + (idx - 196608); dst = (ushortT*)((char*)wsi + OFF_WHH) + (idx - 196608); }
  float4v v = *(const float4v*)src;
  ushort4v o;
  o[0] = f2bf(v[0]); o[1] = f2bf(v[1]); o[2] = f2bf(v[2]); o[3] = f2bf(v[3]);
  *(ushort4v*)dst = o;
}

// ---------------- k_gemm: gi[p] = bf16( x[mti[p]] @ W_ih^T )  (gather fused) ----------------
__global__ __launch_bounds__(256, 2) void k_gemm(const float* __restrict__ x, int* __restrict__ wsi) {
  const int K = wsi[0];
  const int m0 = blockIdx.x * 128;
  if (m0 >= K) return;
  const int n0 = blockIdx.y * 128;
  char* wsc = (char*)wsi;
  const ushortT* Bw = (const ushortT*)(wsc + OFF_WIH);
  ushortT* C = (ushortT*)(wsc + OFF_GI);
  __shared__ ushortT As[128 * 72], Bs[128 * 72];
  __shared__ int mti_s[128];
  const int tid = threadIdx.x, w = tid >> 6, lane = tid & 63;
  const int l15 = lane & 15, quad = lane >> 4;
  if (tid < 128) {
    int m = m0 + tid;
    mti_s[tid] = (m < K) ? wsi[OFF_MTI / 4 + m] : 0;
  }
  float4v acc[4][4];
#pragma unroll
  for (int i = 0; i < 4; ++i)
#pragma unroll
    for (int j = 0; j < 4; ++j) acc[i][j] = (float4v){0.f, 0.f, 0.f, 0.f};

  for (int k0 = 0; k0 < 256; k0 += 64) {
    __syncthreads();
#pragma unroll
    for (int i = 0; i < 8; ++i) {          // A: gather 128 rows x 64 k (fp32 -> bf16)
      int cid = i * 256 + tid;
      int row = cid >> 4, c4 = cid & 15;
      float4v v = *(const float4v*)(x + (size_t)mti_s[row] * 256 + k0 + c4 * 4);
      ushort4v o;
      o[0] = f2bf(v[0]); o[1] = f2bf(v[1]); o[2] = f2bf(v[2]); o[3] = f2bf(v[3]);
      *(ushort4v*)(As + row * 72 + c4 * 4) = o;
    }
#pragma unroll
    for (int i = 0; i < 4; ++i) {          // B: W_ih bf16
      int cid = i * 256 + tid;
      int row = cid >> 3, c8 = cid & 7;
      int4v vb = *(const int4v*)(Bw + (size_t)(n0 + row) * 256 + k0 + c8 * 8);
      *(int4v*)(Bs + row * 72 + c8 * 8) = vb;
    }
    __syncthreads();
#pragma unroll
    for (int kk = 0; kk < 2; ++kk) {
      short8 af[4], bfr[4];
#pragma unroll
      for (int i = 0; i < 4; ++i)
        af[i] = *(const short8*)(As + ((w >> 1) * 64 + i * 16 + l15) * 72 + kk * 32 + quad * 8);
#pragma unroll
      for (int j = 0; j < 4; ++j)
        bfr[j] = *(const short8*)(Bs + ((w & 1) * 64 + j * 16 + l15) * 72 + kk * 32 + quad * 8);
#pragma unroll
      for (int i = 0; i < 4; ++i)
#pragma unroll
        for (int j = 0; j < 4; ++j)
          acc[i][j] = __builtin_amdgcn_mfma_f32_16x16x32_bf16(af[i], bfr[j], acc[i][j], 0, 0, 0);
    }
  }
#pragma unroll
  for (int i = 0; i < 4; ++i) {
    int m = m0 + (w >> 1) * 64 + i * 16 + quad * 4;
#pragma unroll
    for (int j = 0; j < 4; ++j) {
      int n = n0 + (w & 1) * 64 + j * 16 + l15;
#pragma unroll
      for (int r = 0; r < 4; ++r)
        if (m + r < K) C[(size_t)(m + r) * 768 + n] = f2bf(acc[i][j][r]);
    }
  }
}

// ---------------- k_rec: per-block-independent GRU recurrence ----------------
// 16 blocks x 512 threads. Block handles 16 batches x full H=256. W_hh slice of
// 96 gate-rows per wave lives in VGPRs (192/thread). h round-trips through LDS
// only; 2 __syncthreads per step, zero inter-block communication.
__global__ __launch_bounds__(512, 2) void k_rec(const float* __restrict__ bih,
                                                const float* __restrict__ bhh,
                                                const float* __restrict__ h0,
                                                int* __restrict__ wsi,
                                                float* __restrict__ out) {
  const int b0 = blockIdx.x * 16;
  const int tid = threadIdx.x;
  const int w = tid >> 6, lane = tid & 63, l15 = lane & 15, quad = lane >> 4;
  char* wsc = (char*)wsi;
  const ushortT* Whh = (const ushortT*)(wsc + OFF_WHH);
  const ushortT* gib = (const ushortT*)(wsc + OFF_GI);
  const int* parr = wsi + OFF_PARR / 4;
  const int* mti = wsi + OFF_MTI / 4;
  const int K = wsi[0];

  __shared__ float gh_s[16 * 770];      // [batch][gate-row], stride 770 (4*770 % 32 == 8)
  __shared__ ushortT hbf[16 * 264];     // [batch][k] bf16
  __shared__ float bih_s[768], bhh_s[768];
  __shared__ int len_s[16];

  for (int i = tid; i < 768; i += 512) { bih_s[i] = bih[i]; bhh_s[i] = bhh[i]; }
  if (tid < 16) len_s[tid] = wsi[OFF_LEN / 4 + b0 + tid];

  // resident W_hh fragments: wave w owns gate-rows [96w, 96w+96) = 6 tiles
  short8 wf[6][8];
#pragma unroll
  for (int tt = 0; tt < 6; ++tt) {
    int n = w * 96 + tt * 16 + l15;
#pragma unroll
    for (int kk = 0; kk < 8; ++kk)
      wf[tt][kk] = *(const short8*)(Whh + n * 256 + kk * 32 + quad * 8);
  }

  // [B]-role ownership: batch bB = tid>>5, cols c0..c0+7
  const int bB = tid >> 5;
  const int bg = b0 + bB;
  const int c0 = (tid & 31) * 8;
  float hreg[8];
  {
    float4v a = *(const float4v*)(h0 + bg * 256 + c0);
    float4v b = *(const float4v*)(h0 + bg * 256 + c0 + 4);
    hreg[0] = a[0]; hreg[1] = a[1]; hreg[2] = a[2]; hreg[3] = a[3];
    hreg[4] = b[0]; hreg[5] = b[1]; hreg[6] = b[2]; hreg[7] = b[3];
    ushort4v p0, p1;
    p0[0] = f2bf(a[0]); p0[1] = f2bf(a[1]); p0[2] = f2bf(a[2]); p0[3] = f2bf(a[3]);
    p1[0] = f2bf(b[0]); p1[1] = f2bf(b[1]); p1[2] = f2bf(b[2]); p1[3] = f2bf(b[3]);
    *(ushort4v*)(hbf + bB * 264 + c0) = p0;
    *(ushort4v*)(hbf + bB * 264 + c0 + 4) = p1;
  }
  __syncthreads();

  int tmax = 0;
#pragma unroll
  for (int i = 0; i < 16; ++i) tmax = max(tmax, len_s[i]);

  // prefetch for t=0
  int pcur = parr[bg];
  int mcur = mti[bg];
  int4v gi_r, gi_z, gi_n;
  {
    size_t pb = (size_t)max(pcur, 0) * 768;
    gi_r = *(const int4v*)(gib + pb + c0);
    gi_z = *(const int4v*)(gib + pb + 256 + c0);
    gi_n = *(const int4v*)(gib + pb + 512 + c0);
  }

  for (int t = 0; t < tmax; ++t) {
    // prefetch step-t+1 metadata (latency hidden under MFMA phase)
    int pnext = -1, mnext = 0;
    if (t + 1 < 512) {
      pnext = parr[(t + 1) * 256 + bg];
      mnext = mti[(t + 1) * 256 + bg];
    }

    // [A] gh = h @ W_hh^T
    float4v acc[6];
#pragma unroll
    for (int tt = 0; tt < 6; ++tt) acc[tt] = (float4v){0.f, 0.f, 0.f, 0.f};
#pragma unroll
    for (int kk = 0; kk < 8; ++kk) {
      short8 a = *(const short8*)((const char*)hbf + l15 * 528 + kk * 64 + quad * 16);
#pragma unroll
      for (int tt = 0; tt < 6; ++tt)
        acc[tt] = __builtin_amdgcn_mfma_f32_16x16x32_bf16(a, wf[tt][kk], acc[tt], 0, 0, 0);
    }
#pragma unroll
    for (int tt = 0; tt < 6; ++tt) {
      int n = w * 96 + tt * 16 + l15;
#pragma unroll
      for (int r = 0; r < 4; ++r)
        gh_s[(quad * 4 + r) * 770 + n] = acc[tt][r];
    }
    __syncthreads();

    // [B] gate nonlinearity + h update
    const bool valid = (t < len_s[bB]);
    const int nflat = t * 256 + bg;
    float4v ghr0 = *(const float4v*)(gh_s + bB * 770 + c0);
    float4v ghr1 = *(const float4v*)(gh_s + bB * 770 + c0 + 4);
    float4v ghz0 = *(const float4v*)(gh_s + bB * 770 + 256 + c0);
    float4v ghz1 = *(const float4v*)(gh_s + bB * 770 + 256 + c0 + 4);
    float4v ghn0 = *(const float4v*)(gh_s + bB * 770 + 512 + c0);
    float4v ghn1 = *(const float4v*)(gh_s + bB * 770 + 512 + c0 + 4);
#pragma unroll
    for (int j = 0; j < 8; ++j) {
      float ghr = (j < 4) ? ghr0[j & 3] : ghr1[j & 3];
      float ghz = (j < 4) ? ghz0[j & 3] : ghz1[j & 3];
      float ghn = (j < 4) ? ghn0[j & 3] : ghn1[j & 3];
      float gr = bf2f((ushortT)(((unsigned)gi_r[j >> 1]) >> ((j & 1) * 16)));
      float gz = bf2f((ushortT)(((unsigned)gi_z[j >> 1]) >> ((j & 1) * 16)));
      float gn = bf2f((ushortT)(((unsigned)gi_n[j >> 1]) >> ((j & 1) * 16)));
      float rr = sigf(gr + bih_s[c0 + j] + ghr + bhh_s[c0 + j]);
      float zz = sigf(gz + bih_s[256 + c0 + j] + ghz + bhh_s[256 + c0 + j]);
      float nn = tanhfast(gn + bih_s[512 + c0 + j] + rr * (ghn + bhh_s[512 + c0 + j]));
      float hv = (1.f - zz) * nn + zz * hreg[j];
      hreg[j] = valid ? hv : hreg[j];
    }
    if (valid && nflat < K) {
      float4v o0 = {hreg[0], hreg[1], hreg[2], hreg[3]};
      float4v o1 = {hreg[4], hreg[5], hreg[6], hreg[7]};
      *(float4v*)(out + (size_t)mcur * 256 + c0) = o0;
      *(float4v*)(out + (size_t)mcur * 256 + c0 + 4) = o1;
    }
    {
      ushort4v p0, p1;
      p0[0] = f2bf(hreg[0]); p0[1] = f2bf(hreg[1]); p0[2] = f2bf(hreg[2]); p0[3] = f2bf(hreg[3]);
      p1[0] = f2bf(hreg[4]); p1[1] = f2bf(hreg[5]); p1[2] = f2bf(hreg[6]); p1[3] = f2bf(hreg[7]);
      *(ushort4v*)(hbf + bB * 264 + c0) = p0;
      *(ushort4v*)(hbf + bB * 264 + c0 + 4) = p1;
    }
    // issue next-step gi loads (complete during next MFMA phase)
    {
      size_t pb = (size_t)max(pnext, 0) * 768;
      gi_r = *(const int4v*)(gib + pb + c0);
      gi_z = *(const int4v*)(gib + pb + 256 + c0);
      gi_n = *(const int4v*)(gib + pb + 512 + c0);
    }
    pcur = pnext; mcur = mnext;
    __syncthreads();
  }

  // h_last
  {
    float4v o0 = {hreg[0], hreg[1], hreg[2], hreg[3]};
    float4v o1 = {hreg[4], hreg[5], hreg[6], hreg[7]};
    *(float4v*)(out + HLAST_OFF + (size_t)bg * 256 + c0) = o0;
    *(float4v*)(out + HLAST_OFF + (size_t)bg * 256 + c0 + 4) = o1;
  }
}

extern "C" void kernel_launch(void* const* d_in, const int* in_sizes, int n_in,
                              void* d_out, int out_size, void* d_ws, size_t ws_size,
                              hipStream_t stream) {
  const float* x = (const float*)d_in[0];
  const float* h0 = (const float*)d_in[1];
  const int* mask = (const int*)d_in[2];
  const float* Wih = (const float*)d_in[3];
  const float* Whh = (const float*)d_in[4];
  const float* bih = (const float*)d_in[5];
  const float* bhh = (const float*)d_in[6];
  float* out = (float*)d_out;
  int* wsi = (int*)d_ws;

  hipMemsetAsync(d_out, 0, (size_t)out_size * 4, stream);  // unmasked / padded positions emit 0

  k_prep<<<1, 512, 0, stream>>>(mask, wsi);
  k_build<<<512, 256, 0, stream>>>(mask, wsi);
  k_wcvt<<<384, 256, 0, stream>>>(Wih, Whh, wsi);
  k_gemm<<<dim3(1024, 6), 256, 0, stream>>>(x, wsi);
  k_rec<<<16, 512, 0, stream>>>(bih, bhh, h0, wsi, out);
}